// Round 3
// baseline (832.135 us; speedup 1.0000x reference)
//
#include <hip/hip_runtime.h>
#include <hip/hip_bf16.h>

typedef __attribute__((ext_vector_type(4))) float float4v;
typedef __attribute__((ext_vector_type(8))) __bf16 bf16x8;
typedef __attribute__((ext_vector_type(4))) unsigned short ushort4v;
typedef __attribute__((ext_vector_type(8))) unsigned short ushort8v;

constexpr int NTOK = 50176;
constexpr int DIM  = 384;
constexpr int HID  = 1536;
constexpr int BM   = 128;
constexpr int NTH  = 512;
constexpr int NBLK = NTOK / BM;   // 392
constexpr int NCH  = 24;          // hidden chunks of 64

// workspace (byte offsets) — pre-swizzled bf16 images (identical layout to R2)
constexpr int IMG_WD  = 0;                  // [32][384] 768B rows, 24576 B
constexpr int IMG_WUP = 24576;              // [384][32] 64B rows,  24576 B
constexpr int IMG_W1  = 49152;              // 24 x [64][384] 768B rows, 49152 B each
constexpr int IMG_W2  = 49152 + 24*49152;   // 24 x [384][64] 128B rows
constexpr size_t WS_NEED = 2408448;
constexpr int NELEMS = 1204224;             // total ushort elems

// LDS byte offsets
constexpr int L_W1 = 0;        // 48K
constexpr int L_W2 = 49152;    // 48K
constexpr int L_HS = 98304;    // 16K  [128][64] bf16, 128B rows, swizzled
constexpr int L_B1 = 114688;   // 6K   f32 bias1
constexpr int L_B2 = 120832;   // 1.5K f32 bias2
constexpr int LDSZ = 122368;

__device__ __forceinline__ unsigned short f2bf(float f) {
  __hip_bfloat16 h = __float2bfloat16(f);
  return *reinterpret_cast<unsigned short*>(&h);
}

__device__ __forceinline__ float gelu_f(float v) {
  float u = 0.7978845608f * (v + 0.044715f * v * v * v);
  float e = __expf(2.0f * u);
  float t = 1.0f - 2.0f / (e + 1.0f);
  return 0.5f * v * (1.0f + t);
}

// 48KB staging granule map: thread t, granule j <-> byte t*16 + j*8192.
// Normal vector loads (L2-allocating — R1 proved 94%+ hit on this image),
// issued one full MFMA phase before the barrier that drains them (T14).
__device__ __forceinline__ void stage_load(const char* src, int tid, ushort8v st[6]) {
  #pragma unroll
  for (int j = 0; j < 6; ++j)
    st[j] = *(const ushort8v*)(src + tid * 16 + j * 8192);
}
__device__ __forceinline__ void stage_write(char* dst, int tid, const ushort8v st[6]) {
  #pragma unroll
  for (int j = 0; j < 6; ++j)
    *(ushort8v*)(dst + tid * 16 + j * 8192) = st[j];
}

// ---------------- pack kernel: f32 weights -> pre-swizzled bf16 images ----------------
__global__ __launch_bounds__(256) void pack_k(
    const float* __restrict__ W1, const float* __restrict__ W2,
    const float* __restrict__ wd, const float* __restrict__ wu,
    unsigned short* __restrict__ img)
{
  int i = blockIdx.x * 256 + threadIdx.x;
  if (i >= NELEMS) return;
  if (i < 12288) {                              // WD: rows r=lora-col (0..31), 768B rows
    int r = i / 384; int inb = (i % 384) * 2;
    int d = (inb ^ ((r & 7) << 4)) >> 1;
    float f = (r < 24) ? wd[(r >> 3) * (DIM * 8) + d * 8 + (r & 7)] : 0.f;
    img[i] = f2bf(f);
  } else if (i < 24576) {                       // WUP: [384 d][32 k], 64B rows, cross-row swz
    int j = i - 12288; int a = j * 2;
    int dh = a >> 7; int b6 = (a >> 6) & 1;
    int d = dh * 2 + (b6 ^ ((dh >> 1) & 1));
    int k = ((a & 63) ^ ((d & 3) << 4)) >> 1;
    float f = (k < 24) ? wu[k * DIM + d] : 0.f;
    img[i] = f2bf(f);
  } else if (i < 24576 + 589824) {              // W1 chunks: [64 F][384 d], 768B rows
    int j = i - 24576; int h = j / 24576; int jc = j % 24576;
    int r = jc / 384; int inb = (jc % 384) * 2;
    int d = (inb ^ ((r & 7) << 4)) >> 1;
    img[i] = f2bf(W1[d * HID + h * 64 + r]);
  } else {                                      // W2 chunks: [384 d][64 k], 128B rows
    int j = i - 24576 - 589824; int h = j / 24576; int jc = j % 24576;
    int dd = jc / 64; int inb = (jc % 64) * 2;
    int k2 = (inb ^ ((dd & 7) << 4)) >> 1;
    img[i] = f2bf(W2[(h * 64 + k2) * DIM + dd]);
  }
}

// ---------------- fused MLP + MoE-LoRA ----------------
__global__ __launch_bounds__(NTH, 2) void fused_k(
    const float* __restrict__ x,
    const float* __restrict__ tp,
    const int*   __restrict__ ti,
    const float* __restrict__ b1,
    const float* __restrict__ b2,
    const unsigned short* __restrict__ img,
    float* __restrict__ out)
{
  extern __shared__ char lds[];
  const int tid = threadIdx.x, wid = tid >> 6, lane = tid & 63;
  const int lrow = lane & 15, g4 = lane >> 4, lkb = g4 * 8;
  const int blockRow = blockIdx.x * BM;
  const char* imgc = (const char*)img;

  ushort8v st[6];   // shared staging regs: alternate W1/W2 roles, 24 VGPRs

  // ---- prologue: biases -> LDS; issue WD+WUP stage load (48KB contiguous) ----
  for (int i = tid; i < HID; i += NTH) ((float*)(lds + L_B1))[i] = b1[i];
  if (tid < DIM) ((float*)(lds + L_B2))[tid] = b2[tid];
  stage_load(imgc + IMG_WD, tid, st);    // lands under x staging

  // ---- X tile f32 -> bf16 -> LDS (swizzled, 768B rows) at base 0 (temp) ----
  {
    const float* xb = x + (size_t)blockRow * DIM;
    #pragma unroll
    for (int it = 0; it < 24; ++it) {
      int idx = it * NTH + tid;
      int row = idx / 96, c4 = idx % 96;
      float4v v = *(const float4v*)(xb + row * DIM + c4 * 4);
      ushort4v u; u[0]=f2bf(v[0]); u[1]=f2bf(v[1]); u[2]=f2bf(v[2]); u[3]=f2bf(v[3]);
      int byte = (row * 768 + c4 * 8) ^ ((row & 7) << 4);
      *(ushort4v*)(lds + byte) = u;
    }
  }
  __syncthreads();

  // ---- X A-fragments -> registers (persist across all chunks) ----
  const int band = wid >> 1, chh = wid & 1;     // G1 wave grid: 4 row-bands x 2 col-halves
  bf16x8 xf[2][12];
  #pragma unroll
  for (int mt = 0; mt < 2; ++mt) {
    int row = band * 32 + mt * 16 + lrow;
    int rb = row * 768, sw = (row & 7) << 4;
    #pragma unroll
    for (int ks = 0; ks < 12; ++ks)
      xf[mt][ks] = *(const bf16x8*)(lds + ((rb + (ks * 32 + lkb) * 2) ^ sw));
  }
  __syncthreads();   // all X reads done before staging writes overwrite region

  // ---- MoE images -> LDS: WD (first 3 granules) -> L_W1, WUP (last 3) -> L_W2 ----
  {
    #pragma unroll
    for (int j = 0; j < 6; ++j) {
      char* d = (j < 3) ? (lds + L_W1 + j * 8192) : (lds + L_W2 + (j - 3) * 8192);
      *(ushort8v*)(d + tid * 16) = st[j];
    }
  }
  stage_load(imgc + IMG_W1, tid, st);    // W1[0]; drained at next barrier (one-time cost)
  __syncthreads();   // WD/WUP visible

  // G1-moe: t1 = X @ WdT  -> [128][32]
  float4v h2[2] = {};
  {
    int rbw = chh * 16 + lrow, sww = (rbw & 7) << 4;
    #pragma unroll
    for (int ks = 0; ks < 12; ++ks) {
      bf16x8 b = *(const bf16x8*)(lds + L_W1 + ((rbw * 768 + (ks * 32 + lkb) * 2) ^ sww));
      h2[0] = __builtin_amdgcn_mfma_f32_16x16x32_bf16(xf[0][ks], b, h2[0], 0, 0, 0);
      h2[1] = __builtin_amdgcn_mfma_f32_16x16x32_bf16(xf[1][ks], b, h2[1], 0, 0, 0);
    }
  }
  // prob * gelu -> Hs cols 0..31
  {
    int col = chh * 16 + lrow; int e = col >> 3;
    #pragma unroll
    for (int mt = 0; mt < 2; ++mt) {
      #pragma unroll
      for (int r = 0; r < 4; ++r) {
        int row = band * 32 + mt * 16 + g4 * 4 + r;
        int token = blockRow + row;
        float p = 0.f;
        if (e < 3) {
          int i0 = ti[token * 2], i1 = ti[token * 2 + 1];
          if (i0 == e) p += tp[token * 2];
          if (i1 == e) p += tp[token * 2 + 1];
        }
        float gv = p * gelu_f(h2[mt][r]);
        int byte = (row * 128 + col * 2) ^ ((row & 7) << 4);
        *(unsigned short*)(lds + L_HS + byte) = f2bf(gv);
      }
    }
  }
  __syncthreads();   // Hs ready; L_W1 (WD) readers done; W1[0] load drained
  stage_write(lds + L_W1, tid, st);      // W1[0] -> W1buf
  stage_load(imgc + IMG_W2, tid, st);    // W2[0]; lands under G2-moe

  // G2-moe: acc += Hs(0..31) @ WupT  (K=32)
  const int wr = wid >> 2, wc = wid & 3;        // G2 wave grid: 2M x 4N
  float4v acc[4][6] = {};
  {
    bf16x8 A[4];
    #pragma unroll
    for (int mt = 0; mt < 4; ++mt) {
      int ra = wr * 64 + mt * 16 + lrow;
      A[mt] = *(const bf16x8*)(lds + L_HS + ((ra * 128 + lkb * 2) ^ ((ra & 7) << 4)));
    }
    #pragma unroll
    for (int nt = 0; nt < 6; ++nt) {
      int rb = wc * 96 + nt * 16 + lrow;
      bf16x8 b = *(const bf16x8*)(lds + L_W2 + ((rb * 64 + lkb * 2) ^ ((rb & 7) << 4)));
      #pragma unroll
      for (int mt = 0; mt < 4; ++mt)
        acc[mt][nt] = __builtin_amdgcn_mfma_f32_16x16x32_bf16(A[mt], b, acc[mt][nt], 0, 0, 0);
    }
  }

  // ---- main loop over 24 hidden chunks (2 barriers/chunk, T14 staging) ----
  for (int h = 0; h < NCH; ++h) {
    __syncthreads();   // A: W1buf=W1[h] visible; W2buf readers done; drains W2[h] load
    stage_write(lds + L_W2, tid, st);                       // W2[h] -> W2buf
    if (h < NCH - 1)
      stage_load(imgc + IMG_W1 + (h + 1) * 49152, tid, st); // W1[h+1]; lands under G1

    // G1: H = X @ W1c -> [128][64]; per-wave 32x32 tile, A from regs
    float4v hv[2][2] = {};
    {
      int r0 = chh * 32 + lrow, r1 = r0 + 16;
      int s0 = (r0 & 7) << 4, s1 = (r1 & 7) << 4;
      #pragma unroll
      for (int ks = 0; ks < 12; ++ks) {
        int ko = (ks * 32 + lkb) * 2;
        bf16x8 b0 = *(const bf16x8*)(lds + L_W1 + ((r0 * 768 + ko) ^ s0));
        bf16x8 b1v= *(const bf16x8*)(lds + L_W1 + ((r1 * 768 + ko) ^ s1));
        hv[0][0] = __builtin_amdgcn_mfma_f32_16x16x32_bf16(xf[0][ks], b0,  hv[0][0], 0, 0, 0);
        hv[0][1] = __builtin_amdgcn_mfma_f32_16x16x32_bf16(xf[0][ks], b1v, hv[0][1], 0, 0, 0);
        hv[1][0] = __builtin_amdgcn_mfma_f32_16x16x32_bf16(xf[1][ks], b0,  hv[1][0], 0, 0, 0);
        hv[1][1] = __builtin_amdgcn_mfma_f32_16x16x32_bf16(xf[1][ks], b1v, hv[1][1], 0, 0, 0);
      }
    }
    // bias + gelu -> Hs
    #pragma unroll
    for (int nt = 0; nt < 2; ++nt) {
      int col = chh * 32 + nt * 16 + lrow;
      float bb = ((const float*)(lds + L_B1))[h * 64 + col];
      #pragma unroll
      for (int mt = 0; mt < 2; ++mt) {
        #pragma unroll
        for (int r = 0; r < 4; ++r) {
          int row = band * 32 + mt * 16 + g4 * 4 + r;
          float gv = gelu_f(hv[mt][nt][r] + bb);
          int byte = (row * 128 + col * 2) ^ ((row & 7) << 4);
          *(unsigned short*)(lds + L_HS + byte) = f2bf(gv);
        }
      }
    }
    __syncthreads();   // B: W2buf + Hs visible; W1buf readers done; drains W1[h+1] load
    if (h < NCH - 1) {
      stage_write(lds + L_W1, tid, st);                       // W1[h+1] -> W1buf
      stage_load(imgc + IMG_W2 + (h + 1) * 49152, tid, st);   // W2[h+1]; lands under G2
    }

    // G2: acc += Hs @ W2c (K=64)
    #pragma unroll
    for (int kk = 0; kk < 2; ++kk) {
      int kb = kk * 32 + lkb;
      bf16x8 A[4];
      #pragma unroll
      for (int mt = 0; mt < 4; ++mt) {
        int ra = wr * 64 + mt * 16 + lrow;
        A[mt] = *(const bf16x8*)(lds + L_HS + ((ra * 128 + kb * 2) ^ ((ra & 7) << 4)));
      }
      #pragma unroll
      for (int nt = 0; nt < 6; ++nt) {
        int rb = wc * 96 + nt * 16 + lrow;
        bf16x8 b = *(const bf16x8*)(lds + L_W2 + ((rb * 128 + kb * 2) ^ ((rb & 7) << 4)));
        #pragma unroll
        for (int mt = 0; mt < 4; ++mt)
          acc[mt][nt] = __builtin_amdgcn_mfma_f32_16x16x32_bf16(A[mt], b, acc[mt][nt], 0, 0, 0);
      }
    }
  }

  // ---- epilogue: + b2, store f32 ----
  #pragma unroll
  for (int nt = 0; nt < 6; ++nt) {
    int col = wc * 96 + nt * 16 + lrow;
    float bb = ((const float*)(lds + L_B2))[col];
    #pragma unroll
    for (int mt = 0; mt < 4; ++mt) {
      #pragma unroll
      for (int r = 0; r < 4; ++r) {
        int row = wr * 64 + mt * 16 + g4 * 4 + r;
        out[(size_t)(blockRow + row) * DIM + col] = acc[mt][nt][r] + bb;
      }
    }
  }
}

extern "C" void kernel_launch(void* const* d_in, const int* in_sizes, int n_in,
                              void* d_out, int out_size, void* d_ws, size_t ws_size,
                              hipStream_t stream) {
  const float* x          = (const float*)d_in[0];
  const float* topk_probs = (const float*)d_in[2];
  const int*   topk_idx   = (const int*)  d_in[3];
  const float* w_down     = (const float*)d_in[4];
  const float* w_up       = (const float*)d_in[5];
  const float* W1         = (const float*)d_in[6];
  const float* b1         = (const float*)d_in[7];
  const float* W2         = (const float*)d_in[8];
  const float* b2         = (const float*)d_in[9];
  float* out = (float*)d_out;

  if (ws_size < WS_NEED) return;

  hipFuncSetAttribute(reinterpret_cast<const void*>(fused_k),
                      hipFuncAttributeMaxDynamicSharedMemorySize, LDSZ);

  unsigned short* img = (unsigned short*)d_ws;
  pack_k<<<(NELEMS + 255) / 256, 256, 0, stream>>>(W1, W2, w_down, w_up, img);
  fused_k<<<NBLK, NTH, LDSZ, stream>>>(x, topk_probs, topk_idx, b1, b2, img, out);
}

// Round 4
// 306.149 us; speedup vs baseline: 2.7181x; 2.7181x over previous
//
#include <hip/hip_runtime.h>
#include <hip/hip_bf16.h>

typedef __attribute__((ext_vector_type(4))) float float4v;
typedef __attribute__((ext_vector_type(8))) __bf16 bf16x8;
typedef __attribute__((ext_vector_type(8))) unsigned short ushort8v;

constexpr int NTOK = 50176;
constexpr int DIM  = 384;
constexpr int HID  = 1536;
constexpr int BM   = 128;
constexpr int NTH  = 512;
constexpr int NBLK = NTOK / BM;   // 392
constexpr int NCH  = 24;          // hidden chunks of 64

// workspace (byte offsets) — pre-swizzled bf16 images (identical to R2/R3, proven)
constexpr int IMG_WD  = 0;                  // [32][384] 768B rows, 24576 B (+WUP right after)
constexpr int IMG_WUP = 24576;              // [384][32] 64B rows,  24576 B
constexpr int IMG_W1  = 49152;              // 24 x [64][384] 768B rows, 49152 B each
constexpr int IMG_W2  = 49152 + 24*49152;   // 24 x [384][64] 128B rows
constexpr size_t WS_NEED = 2408448;
constexpr int NELEMS = 1204224;

// LDS byte offsets — 160 KiB exactly
constexpr int L_X  = 0;        // 96K  X [128][384] bf16, 768B rows, swizzled (persistent)
constexpr int L_W  = 98304;    // 48K  single W buffer (W1/W2/WD+WUP modes)
constexpr int L_HS = 147456;   // 16K  Hs [128][64] bf16, 128B rows, swizzled
constexpr int LDSZ = 163840;

__device__ __forceinline__ unsigned short f2bf(float f) {
  __hip_bfloat16 h = __float2bfloat16(f);
  return *reinterpret_cast<unsigned short*>(&h);
}

__device__ __forceinline__ float gelu_f(float v) {
  float u = 0.7978845608f * (v + 0.044715f * v * v * v);
  float e = __expf(2.0f * u);
  float t = 1.0f - 2.0f / (e + 1.0f);
  return 0.5f * v * (1.0f + t);
}

// 48KB staging: thread t, granule j <-> byte t*16 + j*8192 (pure linear copy)
__device__ __forceinline__ void stage_load(const char* src, int tid, ushort8v st[6]) {
  #pragma unroll
  for (int j = 0; j < 6; ++j)
    st[j] = *(const ushort8v*)(src + tid * 16 + j * 8192);
}
__device__ __forceinline__ void stage_write(char* dst, int tid, const ushort8v st[6]) {
  #pragma unroll
  for (int j = 0; j < 6; ++j)
    *(ushort8v*)(dst + tid * 16 + j * 8192) = st[j];
}

// ---------------- pack kernel: f32 weights -> pre-swizzled bf16 images (unchanged) ----------------
__global__ __launch_bounds__(256) void pack_k(
    const float* __restrict__ W1, const float* __restrict__ W2,
    const float* __restrict__ wd, const float* __restrict__ wu,
    unsigned short* __restrict__ img)
{
  int i = blockIdx.x * 256 + threadIdx.x;
  if (i >= NELEMS) return;
  if (i < 12288) {                              // WD: rows r=lora-col (0..31), 768B rows
    int r = i / 384; int inb = (i % 384) * 2;
    int d = (inb ^ ((r & 7) << 4)) >> 1;
    float f = (r < 24) ? wd[(r >> 3) * (DIM * 8) + d * 8 + (r & 7)] : 0.f;
    img[i] = f2bf(f);
  } else if (i < 24576) {                       // WUP: [384 d][32 k], 64B rows, cross-row swz
    int j = i - 12288; int a = j * 2;
    int dh = a >> 7; int b6 = (a >> 6) & 1;
    int d = dh * 2 + (b6 ^ ((dh >> 1) & 1));
    int k = ((a & 63) ^ ((d & 3) << 4)) >> 1;
    float f = (k < 24) ? wu[k * DIM + d] : 0.f;
    img[i] = f2bf(f);
  } else if (i < 24576 + 589824) {              // W1 chunks: [64 F][384 d], 768B rows
    int j = i - 24576; int h = j / 24576; int jc = j % 24576;
    int r = jc / 384; int inb = (jc % 384) * 2;
    int d = (inb ^ ((r & 7) << 4)) >> 1;
    img[i] = f2bf(W1[d * HID + h * 64 + r]);
  } else {                                      // W2 chunks: [384 d][64 k], 128B rows
    int j = i - 24576 - 589824; int h = j / 24576; int jc = j % 24576;
    int dd = jc / 64; int inb = (jc % 64) * 2;
    int k2 = (inb ^ ((dd & 7) << 4)) >> 1;
    img[i] = f2bf(W2[(h * 64 + k2) * DIM + dd]);
  }
}

// ---------------- fused MLP + MoE-LoRA ----------------
__global__ __launch_bounds__(NTH, 2) void fused_k(
    const float* __restrict__ x,
    const float* __restrict__ tp,
    const int*   __restrict__ ti,
    const float* __restrict__ b1,
    const float* __restrict__ b2,
    const unsigned short* __restrict__ img,
    float* __restrict__ out)
{
  extern __shared__ char lds[];
  const int tid = threadIdx.x, wid = tid >> 6, lane = tid & 63;
  const int lrow = lane & 15, g4 = lane >> 4, lkb = g4 * 8;
  const int blockRow = blockIdx.x * BM;
  const char* imgc = (const char*)img;

  ushort8v st[6];   // 24 VGPRs staging; alternates WD+WUP / W1 / W2 roles

  // ---- prologue: issue WD+WUP (48KB contiguous); stage X f32->bf16->LDS (b128 writes) ----
  stage_load(imgc + IMG_WD, tid, st);          // lands under X staging
  {
    const float* xb = x + (size_t)blockRow * DIM;
    #pragma unroll
    for (int it = 0; it < 12; ++it) {
      int idx = it * NTH + tid;
      int row = idx / 48, c8 = idx % 48;
      float4v v0 = *(const float4v*)(xb + row * DIM + c8 * 8);
      float4v v1 = *(const float4v*)(xb + row * DIM + c8 * 8 + 4);
      ushort8v u;
      u[0]=f2bf(v0[0]); u[1]=f2bf(v0[1]); u[2]=f2bf(v0[2]); u[3]=f2bf(v0[3]);
      u[4]=f2bf(v1[0]); u[5]=f2bf(v1[1]); u[6]=f2bf(v1[2]); u[7]=f2bf(v1[3]);
      int byte = (row * 768 + c8 * 16) ^ ((row & 7) << 4);
      *(ushort8v*)(lds + L_X + byte) = u;
    }
  }
  __syncthreads();                             // X visible; WD+WUP load drained
  stage_write(lds + L_W, tid, st);             // WD (0..24K) + WUP (24K..48K)
  __syncthreads();                             // WD/WUP visible
  stage_load(imgc + IMG_W1, tid, st);          // W1[0]; lands under MoE compute

  // ---- G1-moe: t1 = X @ WdT -> [128][32] ----
  const int band = wid >> 1, chh = wid & 1;    // G1 grid: 4 row-bands x 2 col-halves
  float4v h2[2] = {};
  {
    int rbw = chh * 16 + lrow, sww = (rbw & 7) << 4;
    int ra0 = band * 32 + lrow, ra1 = ra0 + 16;
    int s0 = (ra0 & 7) << 4, s1 = (ra1 & 7) << 4;
    #pragma unroll
    for (int ks = 0; ks < 12; ++ks) {
      int ko = (ks * 32 + lkb) * 2;
      bf16x8 a0 = *(const bf16x8*)(lds + L_X + ((ra0 * 768 + ko) ^ s0));
      bf16x8 a1 = *(const bf16x8*)(lds + L_X + ((ra1 * 768 + ko) ^ s1));
      bf16x8 b  = *(const bf16x8*)(lds + L_W + ((rbw * 768 + ko) ^ sww));
      h2[0] = __builtin_amdgcn_mfma_f32_16x16x32_bf16(a0, b, h2[0], 0, 0, 0);
      h2[1] = __builtin_amdgcn_mfma_f32_16x16x32_bf16(a1, b, h2[1], 0, 0, 0);
    }
  }
  // prob * gelu -> Hs cols 0..31
  {
    int col = chh * 16 + lrow; int e = col >> 3;
    #pragma unroll
    for (int mt = 0; mt < 2; ++mt) {
      #pragma unroll
      for (int r = 0; r < 4; ++r) {
        int row = band * 32 + mt * 16 + g4 * 4 + r;
        int token = blockRow + row;
        float p = 0.f;
        if (e < 3) {
          int i0 = ti[token * 2], i1 = ti[token * 2 + 1];
          if (i0 == e) p += tp[token * 2];
          if (i1 == e) p += tp[token * 2 + 1];
        }
        float gv = p * gelu_f(h2[mt][r]);
        int byte = (row * 128 + col * 2) ^ ((row & 7) << 4);
        *(unsigned short*)(lds + L_HS + byte) = f2bf(gv);
      }
    }
  }
  __syncthreads();                             // Hs visible; W1[0] load drained (free-ish)

  // ---- G2-moe: acc = Hs(0..31) @ WupT (K=32); WUP at L_W+24576 ----
  const int wr = wid >> 2, wc = wid & 3;       // G2 grid: 2M x 4N
  float4v acc[4][6] = {};
  {
    bf16x8 A[4];
    #pragma unroll
    for (int mt = 0; mt < 4; ++mt) {
      int ra = wr * 64 + mt * 16 + lrow;
      A[mt] = *(const bf16x8*)(lds + L_HS + ((ra * 128 + lkb * 2) ^ ((ra & 7) << 4)));
    }
    #pragma unroll
    for (int nt = 0; nt < 6; ++nt) {
      int rb = wc * 96 + nt * 16 + lrow;
      bf16x8 b = *(const bf16x8*)(lds + L_W + 24576 + ((rb * 64 + lkb * 2) ^ ((rb & 7) << 4)));
      #pragma unroll
      for (int mt = 0; mt < 4; ++mt)
        acc[mt][nt] = __builtin_amdgcn_mfma_f32_16x16x32_bf16(A[mt], b, acc[mt][nt], 0, 0, 0);
    }
  }

  // ---- main loop: 4 barriers/chunk, loads issued right AFTER barriers (land under MFMA) ----
  for (int h = 0; h < NCH; ++h) {
    __syncthreads();                           // (a) L_W readers (G2/moe) done
    stage_write(lds + L_W, tid, st);           // W1[h] -> Wbuf
    __syncthreads();                           // (b) W1[h] visible
    stage_load(imgc + IMG_W2 + h * 49152, tid, st);   // W2[h]; lands under G1

    // G1: H = X @ W1c -> [128][64]
    float4v hv[2][2] = {};
    {
      int ra0 = band * 32 + lrow, ra1 = ra0 + 16;
      int s0 = (ra0 & 7) << 4, s1 = (ra1 & 7) << 4;
      int rb0 = chh * 32 + lrow, rb1 = rb0 + 16;
      int t0 = (rb0 & 7) << 4, t1 = (rb1 & 7) << 4;
      #pragma unroll
      for (int ks = 0; ks < 12; ++ks) {
        int ko = (ks * 32 + lkb) * 2;
        bf16x8 a0 = *(const bf16x8*)(lds + L_X + ((ra0 * 768 + ko) ^ s0));
        bf16x8 a1 = *(const bf16x8*)(lds + L_X + ((ra1 * 768 + ko) ^ s1));
        bf16x8 b0 = *(const bf16x8*)(lds + L_W + ((rb0 * 768 + ko) ^ t0));
        bf16x8 b1v= *(const bf16x8*)(lds + L_W + ((rb1 * 768 + ko) ^ t1));
        hv[0][0] = __builtin_amdgcn_mfma_f32_16x16x32_bf16(a0, b0,  hv[0][0], 0, 0, 0);
        hv[0][1] = __builtin_amdgcn_mfma_f32_16x16x32_bf16(a0, b1v, hv[0][1], 0, 0, 0);
        hv[1][0] = __builtin_amdgcn_mfma_f32_16x16x32_bf16(a1, b0,  hv[1][0], 0, 0, 0);
        hv[1][1] = __builtin_amdgcn_mfma_f32_16x16x32_bf16(a1, b1v, hv[1][1], 0, 0, 0);
      }
    }
    // bias + gelu -> Hs (b1 scalar from global; L2-resident)
    #pragma unroll
    for (int nt = 0; nt < 2; ++nt) {
      int col = chh * 32 + nt * 16 + lrow;
      float bb = b1[h * 64 + col];
      #pragma unroll
      for (int mt = 0; mt < 2; ++mt) {
        #pragma unroll
        for (int r = 0; r < 4; ++r) {
          int row = band * 32 + mt * 16 + g4 * 4 + r;
          float gv = gelu_f(hv[mt][nt][r] + bb);
          int byte = (row * 128 + col * 2) ^ ((row & 7) << 4);
          *(unsigned short*)(lds + L_HS + byte) = f2bf(gv);
        }
      }
    }
    __syncthreads();                           // (c) Hs visible; W1 readers done; W2[h] drained
    stage_write(lds + L_W, tid, st);           // W2[h] -> Wbuf
    __syncthreads();                           // (d) W2[h] visible
    if (h < NCH - 1)
      stage_load(imgc + IMG_W1 + (h + 1) * 49152, tid, st);  // W1[h+1]; lands under G2

    // G2: acc += Hs @ W2c (K=64)
    #pragma unroll
    for (int kk = 0; kk < 2; ++kk) {
      int kb = kk * 32 + lkb;
      bf16x8 A[4];
      #pragma unroll
      for (int mt = 0; mt < 4; ++mt) {
        int ra = wr * 64 + mt * 16 + lrow;
        A[mt] = *(const bf16x8*)(lds + L_HS + ((ra * 128 + kb * 2) ^ ((ra & 7) << 4)));
      }
      #pragma unroll
      for (int nt = 0; nt < 6; ++nt) {
        int rb = wc * 96 + nt * 16 + lrow;
        bf16x8 b = *(const bf16x8*)(lds + L_W + ((rb * 128 + kb * 2) ^ ((rb & 7) << 4)));
        #pragma unroll
        for (int mt = 0; mt < 4; ++mt)
          acc[mt][nt] = __builtin_amdgcn_mfma_f32_16x16x32_bf16(A[mt], b, acc[mt][nt], 0, 0, 0);
      }
    }
  }

  // ---- epilogue: + b2 (global), store f32 ----
  #pragma unroll
  for (int nt = 0; nt < 6; ++nt) {
    int col = wc * 96 + nt * 16 + lrow;
    float bb = b2[col];
    #pragma unroll
    for (int mt = 0; mt < 4; ++mt) {
      #pragma unroll
      for (int r = 0; r < 4; ++r) {
        int row = wr * 64 + mt * 16 + g4 * 4 + r;
        out[(size_t)(blockRow + row) * DIM + col] = acc[mt][nt][r] + bb;
      }
    }
  }
}

extern "C" void kernel_launch(void* const* d_in, const int* in_sizes, int n_in,
                              void* d_out, int out_size, void* d_ws, size_t ws_size,
                              hipStream_t stream) {
  const float* x          = (const float*)d_in[0];
  const float* topk_probs = (const float*)d_in[2];
  const int*   topk_idx   = (const int*)  d_in[3];
  const float* w_down     = (const float*)d_in[4];
  const float* w_up       = (const float*)d_in[5];
  const float* W1         = (const float*)d_in[6];
  const float* b1         = (const float*)d_in[7];
  const float* W2         = (const float*)d_in[8];
  const float* b2         = (const float*)d_in[9];
  float* out = (float*)d_out;

  if (ws_size < WS_NEED) return;

  hipFuncSetAttribute(reinterpret_cast<const void*>(fused_k),
                      hipFuncAttributeMaxDynamicSharedMemorySize, LDSZ);

  unsigned short* img = (unsigned short*)d_ws;
  pack_k<<<(NELEMS + 255) / 256, 256, 0, stream>>>(W1, W2, w_down, w_up, img);
  fused_k<<<NBLK, NTH, LDSZ, stream>>>(x, topk_probs, topk_idx, b1, b2, img, out);
}